// Round 7
// baseline (3913.927 us; speedup 1.0000x reference)
//
#include <hip/hip_runtime.h>
#include <hip/hip_bf16.h>

// Problem constants
#define BB 2048      // batch
#define TIN 365      // input time steps
#define TO 366       // conv output time steps (all three layers)
#define C1 128
#define C2 256
#define C3 128
#define FF 128

typedef __attribute__((ext_vector_type(4))) float f32x4v;
typedef __attribute__((ext_vector_type(8))) short bf16x8;

__device__ inline unsigned short f2bf(float v) {
  unsigned u = __float_as_uint(v);
  unsigned r = (u + 0x7FFF + ((u >> 16) & 1)) >> 16;
  return (unsigned short)r;
}
__device__ inline float bf2f(unsigned short b) {
  return __uint_as_float(((unsigned)b) << 16);
}

// ---------- weight transpose (fp32 fallback): w (Cout,Cin,Kw) -> wt[(i*Kw+k)*Cout+o] ----------
__global__ void wtrans_kernel(const float* __restrict__ wsrc, float* __restrict__ wdst,
                              int Cout, int Cin, int Kw) {
  int n = Cout * Cin * Kw;
  for (int idx = blockIdx.x * 256 + threadIdx.x; idx < n; idx += gridDim.x * 256) {
    int o = idx % Cout;
    int rest = idx / Cout;
    int k = rest % Kw;
    int i = rest / Kw;
    wdst[idx] = wsrc[(o * Cin + i) * Kw + k];
  }
}

// ---------- MFMA weight prepack: hi/lo bf16, per-lane fragment layout ----------
__global__ void wprep2_kernel(const float* __restrict__ w2,
                              short* __restrict__ wh, short* __restrict__ wl) {
  int n = 256 * 128 * 5;
  for (int idx = blockIdx.x * 256 + threadIdx.x; idx < n; idx += gridDim.x * 256) {
    int k = idx % 5;
    int rest = idx / 5;
    int i = rest % 128;
    int o = rest / 128;
    float v = w2[idx];
    unsigned short hb = f2bf(v);
    unsigned short lb = f2bf(v - bf2f(hb));
    size_t dst = ((((size_t)k * 4 + (i >> 5)) * 16 + (o >> 4)) * 64 +
                  ((i >> 3) & 3) * 16 + (o & 15)) * 8 + (i & 7);
    wh[dst] = (short)hb;
    wl[dst] = (short)lb;
  }
}
__global__ void wprep3_kernel(const float* __restrict__ w3,
                              short* __restrict__ wh, short* __restrict__ wl) {
  int n = 128 * 256 * 3;
  for (int idx = blockIdx.x * 256 + threadIdx.x; idx < n; idx += gridDim.x * 256) {
    int k = idx % 3;
    int rest = idx / 3;
    int i = rest % 256;
    int o = rest / 256;
    float v = w3[idx];
    unsigned short hb = f2bf(v);
    unsigned short lb = f2bf(v - bf2f(hb));
    size_t dst = ((((size_t)k * 8 + (i >> 5)) * 8 + (o >> 4)) * 64 +
                  ((i >> 3) & 3) * 16 + (o & 15)) * 8 + (i & 7);
    wh[dst] = (short)hb;
    wl[dst] = (short)lb;
  }
}

// ---------- fold BN stats: y = max(0, scale*x + shift) ----------
__global__ void bnparam_kernel(const double* __restrict__ sums,
                               const float* __restrict__ gamma,
                               const float* __restrict__ beta, int Cch,
                               float* __restrict__ scale, float* __restrict__ shift) {
  int i = threadIdx.x;
  if (i < Cch) {
    const double N = (double)BB * (double)TO;
    double mean = sums[i] / N;
    double var = sums[Cch + i] / N - mean * mean;
    double sc = (double)gamma[i] / sqrt(var + 1e-5);
    scale[i] = (float)sc;
    shift[i] = (float)((double)beta[i] - mean * sc);
  }
}

// ---------- conv1 stats only. grid 256, 8 batches per block ----------
__global__ __launch_bounds__(256) void conv1_stats_kernel(
    const float* __restrict__ x, const float* __restrict__ w1,
    const float* __restrict__ b1, double* __restrict__ sums) {
  __shared__ float4 xs[374];
  __shared__ float ws1[4096];
  int tid = threadIdx.x;
  for (int i = tid; i < 4096; i += 256) ws1[i] = w1[i];
  __syncthreads();
  const int o = tid >> 1, half = tid & 1;
  float wr[32];
#pragma unroll
  for (int i = 0; i < 32; ++i) wr[i] = ws1[o * 32 + i];
  const float bo = b1[o];
  float s1 = 0.f, s2 = 0.f;
  for (int b = blockIdx.x * 8; b < blockIdx.x * 8 + 8; ++b) {
    __syncthreads();
    for (int u = tid; u < 374; u += 256) {
      int t_in = u - 4;
      float4 v = make_float4(0.f, 0.f, 0.f, 0.f);
      if (t_in >= 0 && t_in < TIN) v = *(const float4*)(x + ((size_t)b * TIN + t_in) * 4);
      xs[u] = v;
    }
    __syncthreads();
    for (int t = half * 183; t < half * 183 + 183; ++t) {
      float acc = bo;
#pragma unroll
      for (int k = 0; k < 8; ++k) {
        float4 xv = xs[t + k];
        acc = fmaf(wr[k], xv.x, acc);
        acc = fmaf(wr[8 + k], xv.y, acc);
        acc = fmaf(wr[16 + k], xv.z, acc);
        acc = fmaf(wr[24 + k], xv.w, acc);
      }
      s1 += acc; s2 += acc * acc;
    }
  }
  s1 += __shfl_xor(s1, 1);
  s2 += __shfl_xor(s2, 1);
  if (half == 0) {
    atomicAdd(&sums[o], (double)s1);
    atomicAdd(&sums[C1 + o], (double)s2);
  }
}

// ---------- conv2 stats via split-bf16 MFMA (+ optional fp32 h2 store). grid (6, 2048) ----------
template <bool STORE>
__global__ __launch_bounds__(256) void conv2_mfma_kernel(
    const float* __restrict__ x, const float* __restrict__ w1g,
    const float* __restrict__ b1, const float* __restrict__ scale1,
    const float* __restrict__ shift1, const short* __restrict__ w2ph,
    const short* __restrict__ w2pl, const float* __restrict__ b2,
    float* __restrict__ p2, float* __restrict__ h2g) {
  __shared__ float ws1[4096];
  __shared__ float4 xwin[76];
  __shared__ __align__(16) short h1h[68 * 72];   // [u][i_local], t = tbase-2+u
  __shared__ __align__(16) short h1l[68 * 72];
  __shared__ float sstat[512];
  const int tid = threadIdx.x;
  const int tt = blockIdx.x, b = blockIdx.y;
  const int tbase = tt * 64;
  const int slice = (b * 6 + tt) & 63;
  const int w = tid >> 6, lane = tid & 63;
  const int q = lane >> 4, l15 = lane & 15;

  for (int i = tid; i < 4096; i += 256) ws1[i] = w1g[i];
  for (int u = tid; u < 76; u += 256) {
    int tx = tbase - 6 + u;
    float4 v = make_float4(0.f, 0.f, 0.f, 0.f);
    if (tx >= 0 && tx < TIN) v = *(const float4*)(x + ((size_t)b * TIN + tx) * 4);
    xwin[u] = v;
  }
  float b2r[4][4];
#pragma unroll
  for (int om = 0; om < 4; ++om)
#pragma unroll
    for (int r = 0; r < 4; ++r) b2r[om][r] = b2[64 * w + om * 16 + q * 4 + r];

  f32x4v acc[4][4];
#pragma unroll
  for (int om = 0; om < 4; ++om)
#pragma unroll
    for (int nt = 0; nt < 4; ++nt) acc[om][nt] = (f32x4v){0.f, 0.f, 0.f, 0.f};

  const int chl = tid >> 2, qt = tid & 3;
  for (int ic2 = 0; ic2 < 2; ++ic2) {
    __syncthreads();
    {
      int ch = ic2 * 64 + chl;
      float sc = scale1[ch], sh = shift1[ch], bo = b1[ch];
      const float* wr = &ws1[ch * 32];
      for (int j = 0; j < 17; ++j) {
        int u = qt * 17 + j;
        int t = tbase - 2 + u;
        float a = bo;
#pragma unroll
        for (int kk = 0; kk < 8; ++kk) {
          float4 xv = xwin[u + kk];
          a = fmaf(wr[kk], xv.x, a);
          a = fmaf(wr[8 + kk], xv.y, a);
          a = fmaf(wr[16 + kk], xv.z, a);
          a = fmaf(wr[24 + kk], xv.w, a);
        }
        float v = (t >= 0 && t < TO) ? fmaxf(fmaf(sc, a, sh), 0.f) : 0.f;
        unsigned short hb = f2bf(v);
        h1h[u * 72 + chl] = (short)hb;
        h1l[u * 72 + chl] = (short)f2bf(v - bf2f(hb));
      }
    }
    __syncthreads();
    for (int k = 0; k < 5; ++k) {
      for (int ic = 0; ic < 2; ++ic) {
        int icg = ic2 * 2 + ic;
        bf16x8 ah[4], al[4];
#pragma unroll
        for (int om = 0; om < 4; ++om) {
          int og = 4 * w + om;
          size_t base = ((((size_t)k * 4 + icg) * 16 + og) * 64 + lane) * 8;
          ah[om] = *(const bf16x8*)(w2ph + base);
          al[om] = *(const bf16x8*)(w2pl + base);
        }
        int ioff = ic * 32 + q * 8;
#pragma unroll
        for (int nt = 0; nt < 4; ++nt) {
          int u = nt * 16 + l15 + k;   // <= 67
          bf16x8 bh = *(const bf16x8*)&h1h[u * 72 + ioff];
          bf16x8 bl = *(const bf16x8*)&h1l[u * 72 + ioff];
#pragma unroll
          for (int om = 0; om < 4; ++om) {
            acc[om][nt] = __builtin_amdgcn_mfma_f32_16x16x32_bf16(ah[om], bh, acc[om][nt], 0, 0, 0);
            acc[om][nt] = __builtin_amdgcn_mfma_f32_16x16x32_bf16(ah[om], bl, acc[om][nt], 0, 0, 0);
            acc[om][nt] = __builtin_amdgcn_mfma_f32_16x16x32_bf16(al[om], bh, acc[om][nt], 0, 0, 0);
          }
        }
      }
    }
  }
  float ts1[16], ts2[16];
#pragma unroll
  for (int i = 0; i < 16; ++i) { ts1[i] = 0.f; ts2[i] = 0.f; }
#pragma unroll
  for (int om = 0; om < 4; ++om)
#pragma unroll
    for (int nt = 0; nt < 4; ++nt) {
      int t = tbase + nt * 16 + l15;
      if (t < TO) {
#pragma unroll
        for (int r = 0; r < 4; ++r) {
          float v = acc[om][nt][r] + b2r[om][r];
          ts1[om * 4 + r] += v;
          ts2[om * 4 + r] += v * v;
          if (STORE) {
            int o = 64 * w + om * 16 + q * 4 + r;
            h2g[((size_t)b * 256 + o) * 368 + t] = v;   // raw conv2 + bias, fp32 lossless
          }
        }
      }
    }
#pragma unroll
  for (int i = 0; i < 16; ++i) {
#pragma unroll
    for (int d = 1; d < 16; d <<= 1) {
      ts1[i] += __shfl_xor(ts1[i], d);
      ts2[i] += __shfl_xor(ts2[i], d);
    }
  }
  if (l15 == 0) {
#pragma unroll
    for (int om = 0; om < 4; ++om)
#pragma unroll
      for (int r = 0; r < 4; ++r) {
        int o = 64 * w + om * 16 + q * 4 + r;
        sstat[o] = ts1[om * 4 + r];
        sstat[256 + o] = ts2[om * 4 + r];
      }
  }
  __syncthreads();
  atomicAdd(&p2[(size_t)tid * 64 + slice], sstat[tid]);
  atomicAdd(&p2[((size_t)tid + 256) * 64 + slice], sstat[tid + 256]);
}

// ---------- conv3-only pass from stored fp32 h2. grid (6, 2048) ----------
// EPI 0: stats3 slice partials. EPI 1: GAP -> pooled. (bit-compatible with fused23 epilogues)
template <int EPI>
__global__ __launch_bounds__(256) void conv3_pass_kernel(
    const float* __restrict__ h2g, const float* __restrict__ scale2,
    const float* __restrict__ shift2, const short* __restrict__ w3ph,
    const short* __restrict__ w3pl, const float* __restrict__ b3,
    const float* __restrict__ scale3, const float* __restrict__ shift3,
    float* __restrict__ p3, float* __restrict__ pooled) {
  __shared__ __align__(16) short h2sh[66 * 264];
  __shared__ __align__(16) short h2sl[66 * 264];
  __shared__ float sstat[256];
  const int tid = threadIdx.x;
  const int tt = blockIdx.x, b = blockIdx.y;
  const int tbase = tt * 64;
  const int slice = (b * 6 + tt) & 63;
  const int w = tid >> 6, lane = tid & 63;
  const int q = lane >> 4, l15 = lane & 15;

  float b3r[2][4], sc3r[2][4], sh3r[2][4];
#pragma unroll
  for (int om = 0; om < 2; ++om)
#pragma unroll
    for (int r = 0; r < 4; ++r) {
      int o = 32 * w + om * 16 + q * 4 + r;
      b3r[om][r] = b3[o];
      if (EPI == 1) { sc3r[om][r] = scale3[o]; sh3r[om][r] = shift3[o]; }
    }

  // stage: bn2+relu(h2) -> hi/lo bf16 LDS. wave w handles channels [w*64, w*64+64).
  for (int cc = 0; cc < 64; ++cc) {
    int ch = w * 64 + cc;
    float sc = scale2[ch], sh = shift2[ch];
    const float* src = h2g + ((size_t)b * 256 + ch) * 368;
    int t2 = tbase - 1 + lane;          // u2 = lane, coalesced 64-lane row read
    float v = 0.f;
    if (t2 >= 0 && t2 < TO) v = fmaxf(fmaf(sc, src[t2], sh), 0.f);
    unsigned short hb = f2bf(v);
    h2sh[lane * 264 + ch] = (short)hb;
    h2sl[lane * 264 + ch] = (short)f2bf(v - bf2f(hb));
    if (lane < 2) {
      int u2 = 64 + lane;
      int t2b = tbase - 1 + u2;
      float vb = 0.f;
      if (t2b >= 0 && t2b < TO) vb = fmaxf(fmaf(sc, src[t2b], sh), 0.f);
      unsigned short hbb = f2bf(vb);
      h2sh[u2 * 264 + ch] = (short)hbb;
      h2sl[u2 * 264 + ch] = (short)f2bf(vb - bf2f(hbb));
    }
  }
  __syncthreads();
  // conv3 MFMA (3-term split), reads h2 u = (nt*16+l15)+k <= 65
  f32x4v acc3[2][4];
#pragma unroll
  for (int om = 0; om < 2; ++om)
#pragma unroll
    for (int nt = 0; nt < 4; ++nt) acc3[om][nt] = (f32x4v){0.f, 0.f, 0.f, 0.f};
  for (int k = 0; k < 3; ++k) {
    for (int icg = 0; icg < 8; ++icg) {
      bf16x8 a3h[2], a3l[2];
#pragma unroll
      for (int om = 0; om < 2; ++om) {
        int og = 2 * w + om;
        size_t base = ((((size_t)k * 8 + icg) * 8 + og) * 64 + lane) * 8;
        a3h[om] = *(const bf16x8*)(w3ph + base);
        a3l[om] = *(const bf16x8*)(w3pl + base);
      }
      int ioff = icg * 32 + q * 8;
#pragma unroll
      for (int nt = 0; nt < 4; ++nt) {
        int u = nt * 16 + l15 + k;
        bf16x8 bh = *(const bf16x8*)&h2sh[u * 264 + ioff];
        bf16x8 bl = *(const bf16x8*)&h2sl[u * 264 + ioff];
#pragma unroll
        for (int om = 0; om < 2; ++om) {
          acc3[om][nt] = __builtin_amdgcn_mfma_f32_16x16x32_bf16(a3h[om], bh, acc3[om][nt], 0, 0, 0);
          acc3[om][nt] = __builtin_amdgcn_mfma_f32_16x16x32_bf16(a3l[om], bh, acc3[om][nt], 0, 0, 0);
          acc3[om][nt] = __builtin_amdgcn_mfma_f32_16x16x32_bf16(a3h[om], bl, acc3[om][nt], 0, 0, 0);
        }
      }
    }
  }
  // epilogue
  if (EPI == 0) {
    float ts1[8], ts2[8];
#pragma unroll
    for (int i = 0; i < 8; ++i) { ts1[i] = 0.f; ts2[i] = 0.f; }
#pragma unroll
    for (int om = 0; om < 2; ++om)
#pragma unroll
      for (int nt = 0; nt < 4; ++nt) {
        int t = tbase + nt * 16 + l15;
        if (t < TO) {
#pragma unroll
          for (int r = 0; r < 4; ++r) {
            float v = acc3[om][nt][r] + b3r[om][r];
            ts1[om * 4 + r] += v;
            ts2[om * 4 + r] += v * v;
          }
        }
      }
#pragma unroll
    for (int i = 0; i < 8; ++i) {
#pragma unroll
      for (int d = 1; d < 16; d <<= 1) {
        ts1[i] += __shfl_xor(ts1[i], d);
        ts2[i] += __shfl_xor(ts2[i], d);
      }
    }
    if (l15 == 0) {
#pragma unroll
      for (int om = 0; om < 2; ++om)
#pragma unroll
        for (int r = 0; r < 4; ++r) {
          int o = 32 * w + om * 16 + q * 4 + r;
          sstat[o] = ts1[om * 4 + r];
          sstat[128 + o] = ts2[om * 4 + r];
        }
    }
    __syncthreads();
    atomicAdd(&p3[(size_t)tid * 64 + slice], sstat[tid]);
  } else {
    float ps[8];
#pragma unroll
    for (int i = 0; i < 8; ++i) ps[i] = 0.f;
#pragma unroll
    for (int om = 0; om < 2; ++om)
#pragma unroll
      for (int nt = 0; nt < 4; ++nt) {
        int t = tbase + nt * 16 + l15;
        if (t < TO) {
#pragma unroll
          for (int r = 0; r < 4; ++r) {
            float v = acc3[om][nt][r] + b3r[om][r];
            ps[om * 4 + r] += fmaxf(fmaf(sc3r[om][r], v, sh3r[om][r]), 0.f);
          }
        }
      }
#pragma unroll
    for (int i = 0; i < 8; ++i) {
#pragma unroll
      for (int d = 1; d < 16; d <<= 1) ps[i] += __shfl_xor(ps[i], d);
    }
    if (l15 == 0) {
#pragma unroll
      for (int om = 0; om < 2; ++om)
#pragma unroll
        for (int r = 0; r < 4; ++r) {
          int o = 32 * w + om * 16 + q * 4 + r;
          atomicAdd(&pooled[(size_t)b * 128 + o], ps[om * 4 + r]);
        }
    }
  }
}

// ---------- fused conv2+conv3 via MFMA (R6 path, used when h2 storage doesn't fit) ----------
template <int EPI>
__global__ __launch_bounds__(256) void fused23_kernel(
    const float* __restrict__ x, const float* __restrict__ w1g,
    const float* __restrict__ b1, const float* __restrict__ scale1,
    const float* __restrict__ shift1, const short* __restrict__ w2ph,
    const short* __restrict__ w2pl, const float* __restrict__ b2,
    const float* __restrict__ scale2, const float* __restrict__ shift2,
    const short* __restrict__ w3ph, const short* __restrict__ w3pl,
    const float* __restrict__ b3, const float* __restrict__ scale3,
    const float* __restrict__ shift3, float* __restrict__ p3,
    float* __restrict__ pooled) {
  __shared__ float4 xwin[80];                    // x[tbase-7+u], u<77
  __shared__ __align__(16) short un[34848];      // union: h1 hi/lo [70][72]x2 | h2 hi/lo [66][264]x2
  __shared__ float bn2s[768];                    // b2 | scale2 | shift2
  __shared__ float sstat[256];
  short* h1h = un;
  short* h1l = un + 70 * 72;
  short* h2sh = un;
  short* h2sl = un + 66 * 264;
  const int tid = threadIdx.x;
  const int tt = blockIdx.x, b = blockIdx.y;
  const int tbase = tt * 64;
  const int slice = (b * 6 + tt) & 63;
  const int w = tid >> 6, lane = tid & 63;
  const int q = lane >> 4, l15 = lane & 15;

  for (int u = tid; u < 77; u += 256) {
    int tx = tbase - 7 + u;
    float4 v = make_float4(0.f, 0.f, 0.f, 0.f);
    if (tx >= 0 && tx < TIN) v = *(const float4*)(x + ((size_t)b * TIN + tx) * 4);
    xwin[u] = v;
  }
  bn2s[tid] = b2[tid];
  bn2s[256 + tid] = scale2[tid];
  bn2s[512 + tid] = shift2[tid];

  float b3r[2][4], sc3r[2][4], sh3r[2][4];
#pragma unroll
  for (int om = 0; om < 2; ++om)
#pragma unroll
    for (int r = 0; r < 4; ++r) {
      int o = 32 * w + om * 16 + q * 4 + r;
      b3r[om][r] = b3[o];
      if (EPI == 1) { sc3r[om][r] = scale3[o]; sh3r[om][r] = shift3[o]; }
    }

  f32x4v acc2[4][5];
#pragma unroll
  for (int om = 0; om < 4; ++om)
#pragma unroll
    for (int nt = 0; nt < 5; ++nt) acc2[om][nt] = (f32x4v){0.f, 0.f, 0.f, 0.f};

  const int chl = tid >> 2, qt = tid & 3;
  for (int ic2 = 0; ic2 < 2; ++ic2) {
    int ch = ic2 * 64 + chl;
    float wr[32];
#pragma unroll
    for (int i = 0; i < 32; ++i) wr[i] = w1g[ch * 32 + i];
    float sc = scale1[ch], sh = shift1[ch], bo = b1[ch];
    __syncthreads();
    for (int j = 0; j < 18; ++j) {
      int u1 = qt * 18 + j;
      if (u1 < 70) {
        int t1 = tbase - 3 + u1;
        float a = bo;
#pragma unroll
        for (int kk = 0; kk < 8; ++kk) {
          float4 xv = xwin[u1 + kk];
          a = fmaf(wr[kk], xv.x, a);
          a = fmaf(wr[8 + kk], xv.y, a);
          a = fmaf(wr[16 + kk], xv.z, a);
          a = fmaf(wr[24 + kk], xv.w, a);
        }
        float v = (t1 >= 0 && t1 < TO) ? fmaxf(fmaf(sc, a, sh), 0.f) : 0.f;
        unsigned short hb = f2bf(v);
        h1h[u1 * 72 + chl] = (short)hb;
        h1l[u1 * 72 + chl] = (short)f2bf(v - bf2f(hb));
      }
    }
    __syncthreads();
    for (int k = 0; k < 5; ++k) {
      for (int ic = 0; ic < 2; ++ic) {
        int icg = ic2 * 2 + ic;
        bf16x8 ah[4], al[4];
#pragma unroll
        for (int om = 0; om < 4; ++om) {
          int og = 4 * w + om;
          size_t base = ((((size_t)k * 4 + icg) * 16 + og) * 64 + lane) * 8;
          ah[om] = *(const bf16x8*)(w2ph + base);
          al[om] = *(const bf16x8*)(w2pl + base);
        }
        int ioff = ic * 32 + q * 8;
#pragma unroll
        for (int nt = 0; nt < 5; ++nt) {
          int u1 = nt * 16 + l15 + k;
          if (u1 > 69) u1 = 69;
          bf16x8 bh = *(const bf16x8*)&h1h[u1 * 72 + ioff];
          bf16x8 bl = *(const bf16x8*)&h1l[u1 * 72 + ioff];
#pragma unroll
          for (int om = 0; om < 4; ++om) {
            acc2[om][nt] = __builtin_amdgcn_mfma_f32_16x16x32_bf16(ah[om], bh, acc2[om][nt], 0, 0, 0);
            acc2[om][nt] = __builtin_amdgcn_mfma_f32_16x16x32_bf16(ah[om], bl, acc2[om][nt], 0, 0, 0);
            acc2[om][nt] = __builtin_amdgcn_mfma_f32_16x16x32_bf16(al[om], bh, acc2[om][nt], 0, 0, 0);
          }
        }
      }
    }
  }
  __syncthreads();
#pragma unroll
  for (int om = 0; om < 4; ++om) {
    int og = 4 * w + om;
#pragma unroll
    for (int nt = 0; nt < 5; ++nt) {
      int u2 = nt * 16 + l15;
      if (u2 < 66) {
        int t2 = tbase - 1 + u2;
        bool valid = (t2 >= 0 && t2 < TO);
#pragma unroll
        for (int rp = 0; rp < 2; ++rp) {
          int o = og * 16 + q * 4 + rp * 2;
          float v0 = 0.f, v1 = 0.f;
          if (valid) {
            v0 = fmaxf(fmaf(bn2s[256 + o], acc2[om][nt][rp * 2] + bn2s[o], bn2s[512 + o]), 0.f);
            v1 = fmaxf(fmaf(bn2s[256 + o + 1], acc2[om][nt][rp * 2 + 1] + bn2s[o + 1], bn2s[512 + o + 1]), 0.f);
          }
          unsigned short hb0 = f2bf(v0), hb1 = f2bf(v1);
          *(unsigned*)&h2sh[u2 * 264 + o] = (unsigned)hb0 | ((unsigned)hb1 << 16);
          *(unsigned*)&h2sl[u2 * 264 + o] =
              (unsigned)f2bf(v0 - bf2f(hb0)) | ((unsigned)f2bf(v1 - bf2f(hb1)) << 16);
        }
      }
    }
  }
  __syncthreads();
  f32x4v acc3[2][4];
#pragma unroll
  for (int om = 0; om < 2; ++om)
#pragma unroll
    for (int nt = 0; nt < 4; ++nt) acc3[om][nt] = (f32x4v){0.f, 0.f, 0.f, 0.f};
  for (int k = 0; k < 3; ++k) {
    for (int icg = 0; icg < 8; ++icg) {
      bf16x8 a3h[2], a3l[2];
#pragma unroll
      for (int om = 0; om < 2; ++om) {
        int og = 2 * w + om;
        size_t base = ((((size_t)k * 8 + icg) * 8 + og) * 64 + lane) * 8;
        a3h[om] = *(const bf16x8*)(w3ph + base);
        a3l[om] = *(const bf16x8*)(w3pl + base);
      }
      int ioff = icg * 32 + q * 8;
#pragma unroll
      for (int nt = 0; nt < 4; ++nt) {
        int u = nt * 16 + l15 + k;
        bf16x8 bh = *(const bf16x8*)&h2sh[u * 264 + ioff];
        bf16x8 bl = *(const bf16x8*)&h2sl[u * 264 + ioff];
#pragma unroll
        for (int om = 0; om < 2; ++om) {
          acc3[om][nt] = __builtin_amdgcn_mfma_f32_16x16x32_bf16(a3h[om], bh, acc3[om][nt], 0, 0, 0);
          acc3[om][nt] = __builtin_amdgcn_mfma_f32_16x16x32_bf16(a3l[om], bh, acc3[om][nt], 0, 0, 0);
          acc3[om][nt] = __builtin_amdgcn_mfma_f32_16x16x32_bf16(a3h[om], bl, acc3[om][nt], 0, 0, 0);
        }
      }
    }
  }
  if (EPI == 0) {
    float ts1[8], ts2[8];
#pragma unroll
    for (int i = 0; i < 8; ++i) { ts1[i] = 0.f; ts2[i] = 0.f; }
#pragma unroll
    for (int om = 0; om < 2; ++om)
#pragma unroll
      for (int nt = 0; nt < 4; ++nt) {
        int t = tbase + nt * 16 + l15;
        if (t < TO) {
#pragma unroll
          for (int r = 0; r < 4; ++r) {
            float v = acc3[om][nt][r] + b3r[om][r];
            ts1[om * 4 + r] += v;
            ts2[om * 4 + r] += v * v;
          }
        }
      }
#pragma unroll
    for (int i = 0; i < 8; ++i) {
#pragma unroll
      for (int d = 1; d < 16; d <<= 1) {
        ts1[i] += __shfl_xor(ts1[i], d);
        ts2[i] += __shfl_xor(ts2[i], d);
      }
    }
    if (l15 == 0) {
#pragma unroll
      for (int om = 0; om < 2; ++om)
#pragma unroll
        for (int r = 0; r < 4; ++r) {
          int o = 32 * w + om * 16 + q * 4 + r;
          sstat[o] = ts1[om * 4 + r];
          sstat[128 + o] = ts2[om * 4 + r];
        }
    }
    __syncthreads();
    atomicAdd(&p3[(size_t)tid * 64 + slice], sstat[tid]);
  } else {
    float ps[8];
#pragma unroll
    for (int i = 0; i < 8; ++i) ps[i] = 0.f;
#pragma unroll
    for (int om = 0; om < 2; ++om)
#pragma unroll
      for (int nt = 0; nt < 4; ++nt) {
        int t = tbase + nt * 16 + l15;
        if (t < TO) {
#pragma unroll
          for (int r = 0; r < 4; ++r) {
            float v = acc3[om][nt][r] + b3r[om][r];
            ps[om * 4 + r] += fmaxf(fmaf(sc3r[om][r], v, sh3r[om][r]), 0.f);
          }
        }
      }
#pragma unroll
    for (int i = 0; i < 8; ++i) {
#pragma unroll
      for (int d = 1; d < 16; d <<= 1) ps[i] += __shfl_xor(ps[i], d);
    }
    if (l15 == 0) {
#pragma unroll
      for (int om = 0; om < 2; ++om)
#pragma unroll
        for (int r = 0; r < 4; ++r) {
          int o = 32 * w + om * 16 + q * 4 + r;
          atomicAdd(&pooled[(size_t)b * 128 + o], ps[om * 4 + r]);
        }
    }
  }
}

// ---------- reduce slice partials -> double sums ----------
__global__ __launch_bounds__(64) void reduce_slices_kernel(
    const float* __restrict__ p, double* __restrict__ sums) {
  int c = blockIdx.x, tid = threadIdx.x;
  double s = (double)p[(size_t)c * 64 + tid];
  for (int d = 32; d > 0; d >>= 1) s += __shfl_down(s, d);
  if (tid == 0) sums[c] = s;
}

// ---------- head: pooled sums -> mean -> fc -> off -> tanh ----------
__global__ __launch_bounds__(128) void head2_kernel(
    const float* __restrict__ pooled, const float* __restrict__ fc_w,
    const float* __restrict__ fc_b, const float* __restrict__ off_w,
    const float* __restrict__ off_b, float* __restrict__ offs) {
  int b = blockIdx.x, tid = threadIdx.x;
  __shared__ float pl[128], feat[128];
  pl[tid] = pooled[(size_t)b * C3 + tid] * (1.0f / 366.0f);
  __syncthreads();
  {
    const float* wr = fc_w + tid * FF;
    float a = fc_b[tid];
    for (int i = 0; i < 128; ++i) a = fmaf(pl[i], wr[i], a);
    feat[tid] = a;
  }
  __syncthreads();
  {
    const float* wr = off_w + tid * FF;
    float z = off_b[tid];
    for (int i = 0; i < 128; ++i) z = fmaf(feat[i], wr[i], z);
    offs[(size_t)b * 128 + tid] = tanhf(z);
  }
}

// ---------- distances + argmin + gather ----------
__global__ __launch_bounds__(256) void dist_kernel(
    const float* __restrict__ x, const float* __restrict__ mask,
    const float* __restrict__ protos, const float* __restrict__ offs,
    float* __restrict__ out) {
  int b = blockIdx.x, tid = threadIdx.x;
  __shared__ float ofl[128];
  __shared__ double dred[256];
  __shared__ int ksel;
  if (tid < 128) ofl[tid] = offs[(size_t)b * 128 + tid];
  __syncthreads();
  int k = tid & 31, tg = tid >> 5;
  float o0 = ofl[k * 4 + 0], o1 = ofl[k * 4 + 1], o2 = ofl[k * 4 + 2], o3 = ofl[k * 4 + 3];
  double acc = 0.0;
  for (int t = tg; t < TIN; t += 8) {
    float4 xv = *(const float4*)(x + ((size_t)b * TIN + t) * 4);
    float4 pv = *(const float4*)(protos + ((size_t)k * TIN + t) * 4);
    float m = mask[(size_t)b * TIN + t];
    float d0 = xv.x - pv.x - o0;
    float d1 = xv.y - pv.y - o1;
    float d2 = xv.z - pv.z - o2;
    float d3 = xv.w - pv.w - o3;
    acc += (double)(m * (d0 * d0 + d1 * d1 + d2 * d2 + d3 * d3));
  }
  dred[tid] = acc;
  __syncthreads();
  if (tid < 32) {
    double s = 0.0;
    for (int g = 0; g < 8; ++g) s += dred[g * 32 + tid];
    dred[tid] = s;
  }
  __syncthreads();
  if (tid == 0) {
    double best = dred[0]; int bi = 0;
    for (int kk = 1; kk < 32; ++kk)
      if (dred[kk] < best) { best = dred[kk]; bi = kk; }  // strict < = first-min
    ksel = bi;
  }
  __syncthreads();
  int km = ksel;
  const float* psrc = protos + (size_t)km * TIN * 4;
  float* dst = out + (size_t)b * TIN * 4;
  for (int u = tid; u < TIN * 4; u += 256)
    dst[u] = psrc[u] + ofl[km * 4 + (u & 3)];
}

extern "C" void kernel_launch(void* const* d_in, const int* in_sizes, int n_in,
                              void* d_out, int out_size, void* d_ws, size_t ws_size,
                              hipStream_t stream) {
  const float* x      = (const float*)d_in[0];
  const float* mask   = (const float*)d_in[2];
  const float* protos = (const float*)d_in[3];
  const float* w1 = (const float*)d_in[4];
  const float* b1 = (const float*)d_in[5];
  const float* g1 = (const float*)d_in[6];
  const float* be1 = (const float*)d_in[7];
  const float* w2 = (const float*)d_in[8];
  const float* b2 = (const float*)d_in[9];
  const float* g2 = (const float*)d_in[10];
  const float* be2 = (const float*)d_in[11];
  const float* w3 = (const float*)d_in[12];
  const float* b3 = (const float*)d_in[13];
  const float* g3 = (const float*)d_in[14];
  const float* be3 = (const float*)d_in[15];
  const float* fc_w = (const float*)d_in[16];
  const float* fc_b = (const float*)d_in[17];
  const float* off_w = (const float*)d_in[18];
  const float* off_b = (const float*)d_in[19];
  float* out = (float*)d_out;
  (void)in_sizes; (void)n_in; (void)out_size;

  char* wsp = (char*)d_ws;
  size_t off = 0;
  auto alloc = [&](size_t bytes) { void* p = wsp + off; off += (bytes + 255) & ~(size_t)255; return p; };
  float* bnp   = (float*)alloc(1024 * 4);
  float* offs  = (float*)alloc((size_t)BB * 128 * 4);
  size_t zero_beg = off;
  double* sums  = (double*)alloc(1024 * 8);
  float* pooled = (float*)alloc((size_t)BB * C3 * 4);
  float* p2     = (float*)alloc((size_t)512 * 64 * 4);
  float* p3     = (float*)alloc((size_t)256 * 64 * 4);
  size_t zero_end = off;
  short* w2ph = (short*)alloc((size_t)256 * 128 * 5 * 2);
  short* w2pl = (short*)alloc((size_t)256 * 128 * 5 * 2);
  short* w3ph = (short*)alloc((size_t)128 * 256 * 3 * 2);
  short* w3pl = (short*)alloc((size_t)128 * 256 * 3 * 2);
  size_t small_end = off;
  const bool mfma_ok = ws_size >= small_end;   // ~3.7 MB
  const size_t h2_bytes = (size_t)BB * 256 * 368 * 4;   // 772 MB fp32
  float* h2 = (float*)(wsp + small_end);
  const bool h2_ok = ws_size >= small_end + h2_bytes;

  double* sums1 = sums;
  double* sums2 = sums + 256;
  double* sums3 = sums + 768;
  float* scale1 = bnp;        float* shift1 = bnp + 128;
  float* scale2 = bnp + 256;  float* shift2 = bnp + 512;
  float* scale3 = bnp + 768;  float* shift3 = bnp + 896;

  hipMemsetAsync(wsp + zero_beg, 0, zero_end - zero_beg, stream);

  conv1_stats_kernel<<<256, 256, 0, stream>>>(x, w1, b1, sums1);
  bnparam_kernel<<<1, 256, 0, stream>>>(sums1, g1, be1, C1, scale1, shift1);

  if (mfma_ok) {
    wprep2_kernel<<<256, 256, 0, stream>>>(w2, w2ph, w2pl);
    wprep3_kernel<<<128, 256, 0, stream>>>(w3, w3ph, w3pl);

    if (h2_ok) {
      conv2_mfma_kernel<true><<<dim3(6, BB), 256, 0, stream>>>(
          x, w1, b1, scale1, shift1, w2ph, w2pl, b2, p2, h2);
      reduce_slices_kernel<<<512, 64, 0, stream>>>(p2, sums2);
      bnparam_kernel<<<1, 256, 0, stream>>>(sums2, g2, be2, C2, scale2, shift2);
      conv3_pass_kernel<0><<<dim3(6, BB), 256, 0, stream>>>(
          h2, scale2, shift2, w3ph, w3pl, b3, scale3, shift3, p3, pooled);
      reduce_slices_kernel<<<256, 64, 0, stream>>>(p3, sums3);
      bnparam_kernel<<<1, 256, 0, stream>>>(sums3, g3, be3, C3, scale3, shift3);
      conv3_pass_kernel<1><<<dim3(6, BB), 256, 0, stream>>>(
          h2, scale2, shift2, w3ph, w3pl, b3, scale3, shift3, p3, pooled);
    } else {
      conv2_mfma_kernel<false><<<dim3(6, BB), 256, 0, stream>>>(
          x, w1, b1, scale1, shift1, w2ph, w2pl, b2, p2, h2);
      reduce_slices_kernel<<<512, 64, 0, stream>>>(p2, sums2);
      bnparam_kernel<<<1, 256, 0, stream>>>(sums2, g2, be2, C2, scale2, shift2);
      fused23_kernel<0><<<dim3(6, BB), 256, 0, stream>>>(
          x, w1, b1, scale1, shift1, w2ph, w2pl, b2, scale2, shift2,
          w3ph, w3pl, b3, scale3, shift3, p3, pooled);
      reduce_slices_kernel<<<256, 64, 0, stream>>>(p3, sums3);
      bnparam_kernel<<<1, 256, 0, stream>>>(sums3, g3, be3, C3, scale3, shift3);
      fused23_kernel<1><<<dim3(6, BB), 256, 0, stream>>>(
          x, w1, b1, scale1, shift1, w2ph, w2pl, b2, scale2, shift2,
          w3ph, w3pl, b3, scale3, shift3, p3, pooled);
    }
  }

  head2_kernel<<<BB, 128, 0, stream>>>(pooled, fc_w, fc_b, off_w, off_b, offs);
  dist_kernel<<<BB, 256, 0, stream>>>(x, mask, protos, offs, out);
}

// Round 8
// 3873.499 us; speedup vs baseline: 1.0104x; 1.0104x over previous
//
#include <hip/hip_runtime.h>
#include <hip/hip_bf16.h>

// Problem constants
#define BB 2048      // batch
#define TIN 365      // input time steps
#define TO 366       // conv output time steps (all three layers)
#define C1 128
#define C2 256
#define C3 128
#define FF 128

typedef __attribute__((ext_vector_type(4))) float f32x4v;
typedef __attribute__((ext_vector_type(8))) short bf16x8;

__device__ inline unsigned short f2bf(float v) {
  unsigned u = __float_as_uint(v);
  unsigned r = (u + 0x7FFF + ((u >> 16) & 1)) >> 16;
  return (unsigned short)r;
}
__device__ inline float bf2f(unsigned short b) {
  return __uint_as_float(((unsigned)b) << 16);
}

// ---------- MFMA weight prepack: hi/lo bf16, per-lane fragment layout ----------
__global__ void wprep2_kernel(const float* __restrict__ w2,
                              short* __restrict__ wh, short* __restrict__ wl) {
  int n = 256 * 128 * 5;
  for (int idx = blockIdx.x * 256 + threadIdx.x; idx < n; idx += gridDim.x * 256) {
    int k = idx % 5;
    int rest = idx / 5;
    int i = rest % 128;
    int o = rest / 128;
    float v = w2[idx];
    unsigned short hb = f2bf(v);
    unsigned short lb = f2bf(v - bf2f(hb));
    size_t dst = ((((size_t)k * 4 + (i >> 5)) * 16 + (o >> 4)) * 64 +
                  ((i >> 3) & 3) * 16 + (o & 15)) * 8 + (i & 7);
    wh[dst] = (short)hb;
    wl[dst] = (short)lb;
  }
}
__global__ void wprep3_kernel(const float* __restrict__ w3,
                              short* __restrict__ wh, short* __restrict__ wl) {
  int n = 128 * 256 * 3;
  for (int idx = blockIdx.x * 256 + threadIdx.x; idx < n; idx += gridDim.x * 256) {
    int k = idx % 3;
    int rest = idx / 3;
    int i = rest % 256;
    int o = rest / 256;
    float v = w3[idx];
    unsigned short hb = f2bf(v);
    unsigned short lb = f2bf(v - bf2f(hb));
    size_t dst = ((((size_t)k * 8 + (i >> 5)) * 8 + (o >> 4)) * 64 +
                  ((i >> 3) & 3) * 16 + (o & 15)) * 8 + (i & 7);
    wh[dst] = (short)hb;
    wl[dst] = (short)lb;
  }
}

// ---------- fold BN stats: y = max(0, scale*x + shift) ----------
__global__ void bnparam_kernel(const double* __restrict__ sums,
                               const float* __restrict__ gamma,
                               const float* __restrict__ beta, int Cch,
                               float* __restrict__ scale, float* __restrict__ shift) {
  int i = threadIdx.x;
  if (i < Cch) {
    const double N = (double)BB * (double)TO;
    double mean = sums[i] / N;
    double var = sums[Cch + i] / N - mean * mean;
    double sc = (double)gamma[i] / sqrt(var + 1e-5);
    scale[i] = (float)sc;
    shift[i] = (float)((double)beta[i] - mean * sc);
  }
}

// ---------- conv1 stats only. grid 256, 8 batches per block ----------
__global__ __launch_bounds__(256) void conv1_stats_kernel(
    const float* __restrict__ x, const float* __restrict__ w1,
    const float* __restrict__ b1, double* __restrict__ sums) {
  __shared__ float4 xs[374];
  __shared__ float ws1[4096];
  int tid = threadIdx.x;
  for (int i = tid; i < 4096; i += 256) ws1[i] = w1[i];
  __syncthreads();
  const int o = tid >> 1, half = tid & 1;
  float wr[32];
#pragma unroll
  for (int i = 0; i < 32; ++i) wr[i] = ws1[o * 32 + i];
  const float bo = b1[o];
  float s1 = 0.f, s2 = 0.f;
  for (int b = blockIdx.x * 8; b < blockIdx.x * 8 + 8; ++b) {
    __syncthreads();
    for (int u = tid; u < 374; u += 256) {
      int t_in = u - 4;
      float4 v = make_float4(0.f, 0.f, 0.f, 0.f);
      if (t_in >= 0 && t_in < TIN) v = *(const float4*)(x + ((size_t)b * TIN + t_in) * 4);
      xs[u] = v;
    }
    __syncthreads();
    for (int t = half * 183; t < half * 183 + 183; ++t) {
      float acc = bo;
#pragma unroll
      for (int k = 0; k < 8; ++k) {
        float4 xv = xs[t + k];
        acc = fmaf(wr[k], xv.x, acc);
        acc = fmaf(wr[8 + k], xv.y, acc);
        acc = fmaf(wr[16 + k], xv.z, acc);
        acc = fmaf(wr[24 + k], xv.w, acc);
      }
      s1 += acc; s2 += acc * acc;
    }
  }
  s1 += __shfl_xor(s1, 1);
  s2 += __shfl_xor(s2, 1);
  if (half == 0) {
    atomicAdd(&sums[o], (double)s1);
    atomicAdd(&sums[C1 + o], (double)s2);
  }
}

// ---------- conv2 stats via split-bf16 MFMA. grid (6, 2048) ----------
__global__ __launch_bounds__(256) void conv2_mfma_kernel(
    const float* __restrict__ x, const float* __restrict__ w1g,
    const float* __restrict__ b1, const float* __restrict__ scale1,
    const float* __restrict__ shift1, const short* __restrict__ w2ph,
    const short* __restrict__ w2pl, const float* __restrict__ b2,
    float* __restrict__ p2) {
  __shared__ float ws1[4096];
  __shared__ float4 xwin[76];
  __shared__ __align__(16) short h1h[68 * 72];   // [u][i_local], t = tbase-2+u
  __shared__ __align__(16) short h1l[68 * 72];
  __shared__ float sstat[512];
  const int tid = threadIdx.x;
  const int tt = blockIdx.x, b = blockIdx.y;
  const int tbase = tt * 64;
  const int slice = (b * 6 + tt) & 63;
  const int w = tid >> 6, lane = tid & 63;
  const int q = lane >> 4, l15 = lane & 15;

  for (int i = tid; i < 4096; i += 256) ws1[i] = w1g[i];
  for (int u = tid; u < 76; u += 256) {
    int tx = tbase - 6 + u;
    float4 v = make_float4(0.f, 0.f, 0.f, 0.f);
    if (tx >= 0 && tx < TIN) v = *(const float4*)(x + ((size_t)b * TIN + tx) * 4);
    xwin[u] = v;
  }
  float b2r[4][4];
#pragma unroll
  for (int om = 0; om < 4; ++om)
#pragma unroll
    for (int r = 0; r < 4; ++r) b2r[om][r] = b2[64 * w + om * 16 + q * 4 + r];

  f32x4v acc[4][4];
#pragma unroll
  for (int om = 0; om < 4; ++om)
#pragma unroll
    for (int nt = 0; nt < 4; ++nt) acc[om][nt] = (f32x4v){0.f, 0.f, 0.f, 0.f};

  const int chl = tid >> 2, qt = tid & 3;
  for (int ic2 = 0; ic2 < 2; ++ic2) {
    __syncthreads();
    {
      int ch = ic2 * 64 + chl;
      float sc = scale1[ch], sh = shift1[ch], bo = b1[ch];
      const float* wr = &ws1[ch * 32];
      for (int j = 0; j < 17; ++j) {
        int u = qt * 17 + j;
        int t = tbase - 2 + u;
        float a = bo;
#pragma unroll
        for (int kk = 0; kk < 8; ++kk) {
          float4 xv = xwin[u + kk];
          a = fmaf(wr[kk], xv.x, a);
          a = fmaf(wr[8 + kk], xv.y, a);
          a = fmaf(wr[16 + kk], xv.z, a);
          a = fmaf(wr[24 + kk], xv.w, a);
        }
        float v = (t >= 0 && t < TO) ? fmaxf(fmaf(sc, a, sh), 0.f) : 0.f;
        unsigned short hb = f2bf(v);
        h1h[u * 72 + chl] = (short)hb;
        h1l[u * 72 + chl] = (short)f2bf(v - bf2f(hb));
      }
    }
    __syncthreads();
    for (int k = 0; k < 5; ++k) {
      for (int ic = 0; ic < 2; ++ic) {
        int icg = ic2 * 2 + ic;
        bf16x8 ah[4], al[4];
#pragma unroll
        for (int om = 0; om < 4; ++om) {
          int og = 4 * w + om;
          size_t base = ((((size_t)k * 4 + icg) * 16 + og) * 64 + lane) * 8;
          ah[om] = *(const bf16x8*)(w2ph + base);
          al[om] = *(const bf16x8*)(w2pl + base);
        }
        int ioff = ic * 32 + q * 8;
#pragma unroll
        for (int nt = 0; nt < 4; ++nt) {
          int u = nt * 16 + l15 + k;   // <= 67
          bf16x8 bh = *(const bf16x8*)&h1h[u * 72 + ioff];
          bf16x8 bl = *(const bf16x8*)&h1l[u * 72 + ioff];
#pragma unroll
          for (int om = 0; om < 4; ++om) {
            acc[om][nt] = __builtin_amdgcn_mfma_f32_16x16x32_bf16(ah[om], bh, acc[om][nt], 0, 0, 0);
            acc[om][nt] = __builtin_amdgcn_mfma_f32_16x16x32_bf16(ah[om], bl, acc[om][nt], 0, 0, 0);
            acc[om][nt] = __builtin_amdgcn_mfma_f32_16x16x32_bf16(al[om], bh, acc[om][nt], 0, 0, 0);
          }
        }
      }
    }
  }
  float ts1[16], ts2[16];
#pragma unroll
  for (int i = 0; i < 16; ++i) { ts1[i] = 0.f; ts2[i] = 0.f; }
#pragma unroll
  for (int om = 0; om < 4; ++om)
#pragma unroll
    for (int nt = 0; nt < 4; ++nt) {
      int t = tbase + nt * 16 + l15;
      if (t < TO) {
#pragma unroll
        for (int r = 0; r < 4; ++r) {
          float v = acc[om][nt][r] + b2r[om][r];
          ts1[om * 4 + r] += v;
          ts2[om * 4 + r] += v * v;
        }
      }
    }
#pragma unroll
  for (int i = 0; i < 16; ++i) {
#pragma unroll
    for (int d = 1; d < 16; d <<= 1) {
      ts1[i] += __shfl_xor(ts1[i], d);
      ts2[i] += __shfl_xor(ts2[i], d);
    }
  }
  if (l15 == 0) {
#pragma unroll
    for (int om = 0; om < 4; ++om)
#pragma unroll
      for (int r = 0; r < 4; ++r) {
        int o = 64 * w + om * 16 + q * 4 + r;
        sstat[o] = ts1[om * 4 + r];
        sstat[256 + o] = ts2[om * 4 + r];
      }
  }
  __syncthreads();
  atomicAdd(&p2[(size_t)tid * 64 + slice], sstat[tid]);
  atomicAdd(&p2[((size_t)tid + 256) * 64 + slice], sstat[tid + 256]);
}

// ---------- fused conv2+conv3 via MFMA. grid (6, 2048) ----------
// EPI 0: stats3 slice-partials (+ optional lossless fp32 h3 store). EPI 1: GAP -> pooled.
template <int EPI, bool STOREH3>
__global__ __launch_bounds__(256) void fused23_kernel(
    const float* __restrict__ x, const float* __restrict__ w1g,
    const float* __restrict__ b1, const float* __restrict__ scale1,
    const float* __restrict__ shift1, const short* __restrict__ w2ph,
    const short* __restrict__ w2pl, const float* __restrict__ b2,
    const float* __restrict__ scale2, const float* __restrict__ shift2,
    const short* __restrict__ w3ph, const short* __restrict__ w3pl,
    const float* __restrict__ b3, const float* __restrict__ scale3,
    const float* __restrict__ shift3, float* __restrict__ p3,
    float* __restrict__ pooled, float* __restrict__ h3g) {
  __shared__ float4 xwin[80];                    // x[tbase-7+u], u<77
  __shared__ __align__(16) short un[34848];      // union: h1 hi/lo [70][72]x2 | h2 hi/lo [66][264]x2
  __shared__ float bn2s[768];                    // b2 | scale2 | shift2
  __shared__ float sstat[256];
  short* h1h = un;
  short* h1l = un + 70 * 72;
  short* h2sh = un;
  short* h2sl = un + 66 * 264;
  const int tid = threadIdx.x;
  const int tt = blockIdx.x, b = blockIdx.y;
  const int tbase = tt * 64;
  const int slice = (b * 6 + tt) & 63;
  const int w = tid >> 6, lane = tid & 63;
  const int q = lane >> 4, l15 = lane & 15;

  for (int u = tid; u < 77; u += 256) {
    int tx = tbase - 7 + u;
    float4 v = make_float4(0.f, 0.f, 0.f, 0.f);
    if (tx >= 0 && tx < TIN) v = *(const float4*)(x + ((size_t)b * TIN + tx) * 4);
    xwin[u] = v;
  }
  bn2s[tid] = b2[tid];
  bn2s[256 + tid] = scale2[tid];
  bn2s[512 + tid] = shift2[tid];

  float b3r[2][4], sc3r[2][4], sh3r[2][4];
#pragma unroll
  for (int om = 0; om < 2; ++om)
#pragma unroll
    for (int r = 0; r < 4; ++r) {
      int o = 32 * w + om * 16 + q * 4 + r;
      b3r[om][r] = b3[o];
      if (EPI == 1) { sc3r[om][r] = scale3[o]; sh3r[om][r] = shift3[o]; }
    }

  f32x4v acc2[4][5];
#pragma unroll
  for (int om = 0; om < 4; ++om)
#pragma unroll
    for (int nt = 0; nt < 5; ++nt) acc2[om][nt] = (f32x4v){0.f, 0.f, 0.f, 0.f};

  const int chl = tid >> 2, qt = tid & 3;
  for (int ic2 = 0; ic2 < 2; ++ic2) {
    int ch = ic2 * 64 + chl;
    float wr[32];
#pragma unroll
    for (int i = 0; i < 32; ++i) wr[i] = w1g[ch * 32 + i];
    float sc = scale1[ch], sh = shift1[ch], bo = b1[ch];
    __syncthreads();
    for (int j = 0; j < 18; ++j) {
      int u1 = qt * 18 + j;
      if (u1 < 70) {
        int t1 = tbase - 3 + u1;
        float a = bo;
#pragma unroll
        for (int kk = 0; kk < 8; ++kk) {
          float4 xv = xwin[u1 + kk];
          a = fmaf(wr[kk], xv.x, a);
          a = fmaf(wr[8 + kk], xv.y, a);
          a = fmaf(wr[16 + kk], xv.z, a);
          a = fmaf(wr[24 + kk], xv.w, a);
        }
        float v = (t1 >= 0 && t1 < TO) ? fmaxf(fmaf(sc, a, sh), 0.f) : 0.f;
        unsigned short hb = f2bf(v);
        h1h[u1 * 72 + chl] = (short)hb;
        h1l[u1 * 72 + chl] = (short)f2bf(v - bf2f(hb));
      }
    }
    __syncthreads();
    for (int k = 0; k < 5; ++k) {
      for (int ic = 0; ic < 2; ++ic) {
        int icg = ic2 * 2 + ic;
        bf16x8 ah[4], al[4];
#pragma unroll
        for (int om = 0; om < 4; ++om) {
          int og = 4 * w + om;
          size_t base = ((((size_t)k * 4 + icg) * 16 + og) * 64 + lane) * 8;
          ah[om] = *(const bf16x8*)(w2ph + base);
          al[om] = *(const bf16x8*)(w2pl + base);
        }
        int ioff = ic * 32 + q * 8;
#pragma unroll
        for (int nt = 0; nt < 5; ++nt) {
          int u1 = nt * 16 + l15 + k;
          if (u1 > 69) u1 = 69;
          bf16x8 bh = *(const bf16x8*)&h1h[u1 * 72 + ioff];
          bf16x8 bl = *(const bf16x8*)&h1l[u1 * 72 + ioff];
#pragma unroll
          for (int om = 0; om < 4; ++om) {
            acc2[om][nt] = __builtin_amdgcn_mfma_f32_16x16x32_bf16(ah[om], bh, acc2[om][nt], 0, 0, 0);
            acc2[om][nt] = __builtin_amdgcn_mfma_f32_16x16x32_bf16(ah[om], bl, acc2[om][nt], 0, 0, 0);
            acc2[om][nt] = __builtin_amdgcn_mfma_f32_16x16x32_bf16(al[om], bh, acc2[om][nt], 0, 0, 0);
          }
        }
      }
    }
  }
  __syncthreads();
#pragma unroll
  for (int om = 0; om < 4; ++om) {
    int og = 4 * w + om;
#pragma unroll
    for (int nt = 0; nt < 5; ++nt) {
      int u2 = nt * 16 + l15;
      if (u2 < 66) {
        int t2 = tbase - 1 + u2;
        bool valid = (t2 >= 0 && t2 < TO);
#pragma unroll
        for (int rp = 0; rp < 2; ++rp) {
          int o = og * 16 + q * 4 + rp * 2;
          float v0 = 0.f, v1 = 0.f;
          if (valid) {
            v0 = fmaxf(fmaf(bn2s[256 + o], acc2[om][nt][rp * 2] + bn2s[o], bn2s[512 + o]), 0.f);
            v1 = fmaxf(fmaf(bn2s[256 + o + 1], acc2[om][nt][rp * 2 + 1] + bn2s[o + 1], bn2s[512 + o + 1]), 0.f);
          }
          unsigned short hb0 = f2bf(v0), hb1 = f2bf(v1);
          *(unsigned*)&h2sh[u2 * 264 + o] = (unsigned)hb0 | ((unsigned)hb1 << 16);
          *(unsigned*)&h2sl[u2 * 264 + o] =
              (unsigned)f2bf(v0 - bf2f(hb0)) | ((unsigned)f2bf(v1 - bf2f(hb1)) << 16);
        }
      }
    }
  }
  __syncthreads();
  f32x4v acc3[2][4];
#pragma unroll
  for (int om = 0; om < 2; ++om)
#pragma unroll
    for (int nt = 0; nt < 4; ++nt) acc3[om][nt] = (f32x4v){0.f, 0.f, 0.f, 0.f};
  for (int k = 0; k < 3; ++k) {
    for (int icg = 0; icg < 8; ++icg) {
      bf16x8 a3h[2], a3l[2];
#pragma unroll
      for (int om = 0; om < 2; ++om) {
        int og = 2 * w + om;
        size_t base = ((((size_t)k * 8 + icg) * 8 + og) * 64 + lane) * 8;
        a3h[om] = *(const bf16x8*)(w3ph + base);
        a3l[om] = *(const bf16x8*)(w3pl + base);
      }
      int ioff = icg * 32 + q * 8;
#pragma unroll
      for (int nt = 0; nt < 4; ++nt) {
        int u = nt * 16 + l15 + k;
        bf16x8 bh = *(const bf16x8*)&h2sh[u * 264 + ioff];
        bf16x8 bl = *(const bf16x8*)&h2sl[u * 264 + ioff];
#pragma unroll
        for (int om = 0; om < 2; ++om) {
          acc3[om][nt] = __builtin_amdgcn_mfma_f32_16x16x32_bf16(a3h[om], bh, acc3[om][nt], 0, 0, 0);
          acc3[om][nt] = __builtin_amdgcn_mfma_f32_16x16x32_bf16(a3l[om], bh, acc3[om][nt], 0, 0, 0);
          acc3[om][nt] = __builtin_amdgcn_mfma_f32_16x16x32_bf16(a3h[om], bl, acc3[om][nt], 0, 0, 0);
        }
      }
    }
  }
  if (EPI == 0) {
    float ts1[8], ts2[8];
#pragma unroll
    for (int i = 0; i < 8; ++i) { ts1[i] = 0.f; ts2[i] = 0.f; }
#pragma unroll
    for (int om = 0; om < 2; ++om)
#pragma unroll
      for (int nt = 0; nt < 4; ++nt) {
        int t = tbase + nt * 16 + l15;
        if (t < TO) {
#pragma unroll
          for (int r = 0; r < 4; ++r) {
            float v = acc3[om][nt][r] + b3r[om][r];
            ts1[om * 4 + r] += v;
            ts2[om * 4 + r] += v * v;
            if (STOREH3) {
              int o = 32 * w + om * 16 + q * 4 + r;
              h3g[((size_t)b * 128 + o) * 368 + t] = v;   // raw conv3 + bias, fp32 lossless
            }
          }
        }
      }
#pragma unroll
    for (int i = 0; i < 8; ++i) {
#pragma unroll
      for (int d = 1; d < 16; d <<= 1) {
        ts1[i] += __shfl_xor(ts1[i], d);
        ts2[i] += __shfl_xor(ts2[i], d);
      }
    }
    if (l15 == 0) {
#pragma unroll
      for (int om = 0; om < 2; ++om)
#pragma unroll
        for (int r = 0; r < 4; ++r) {
          int o = 32 * w + om * 16 + q * 4 + r;
          sstat[o] = ts1[om * 4 + r];
          sstat[128 + o] = ts2[om * 4 + r];
        }
    }
    __syncthreads();
    atomicAdd(&p3[(size_t)tid * 64 + slice], sstat[tid]);
  } else {
    float ps[8];
#pragma unroll
    for (int i = 0; i < 8; ++i) ps[i] = 0.f;
#pragma unroll
    for (int om = 0; om < 2; ++om)
#pragma unroll
      for (int nt = 0; nt < 4; ++nt) {
        int t = tbase + nt * 16 + l15;
        if (t < TO) {
#pragma unroll
          for (int r = 0; r < 4; ++r) {
            float v = acc3[om][nt][r] + b3r[om][r];
            ps[om * 4 + r] += fmaxf(fmaf(sc3r[om][r], v, sh3r[om][r]), 0.f);
          }
        }
      }
#pragma unroll
    for (int i = 0; i < 8; ++i) {
#pragma unroll
      for (int d = 1; d < 16; d <<= 1) ps[i] += __shfl_xor(ps[i], d);
    }
    if (l15 == 0) {
#pragma unroll
      for (int om = 0; om < 2; ++om)
#pragma unroll
        for (int r = 0; r < 4; ++r) {
          int o = 32 * w + om * 16 + q * 4 + r;
          atomicAdd(&pooled[(size_t)b * 128 + o], ps[om * 4 + r]);
        }
    }
  }
}

// ---------- GAP from stored fp32 h3. grid 2048, 256 thr, wave-per-32-channels ----------
__global__ __launch_bounds__(256) void gap3_kernel(
    const float* __restrict__ h3g, const float* __restrict__ scale3,
    const float* __restrict__ shift3, float* __restrict__ pooled) {
  int b = blockIdx.x, tid = threadIdx.x;
  int w = tid >> 6, lane = tid & 63;
  for (int cc = 0; cc < 32; ++cc) {
    int ch = w * 32 + cc;
    float sc = scale3[ch], sh = shift3[ch];
    const float* row = h3g + ((size_t)b * 128 + ch) * 368;
    float s = 0.f;
    for (int u = lane; u < TO; u += 64)           // coalesced 64-lane reads
      s += fmaxf(fmaf(sc, row[u], sh), 0.f);
#pragma unroll
    for (int d = 32; d > 0; d >>= 1) s += __shfl_xor(s, d);
    if (lane == 0) pooled[(size_t)b * 128 + ch] = s;
  }
}

// ---------- reduce slice partials -> double sums ----------
__global__ __launch_bounds__(64) void reduce_slices_kernel(
    const float* __restrict__ p, double* __restrict__ sums) {
  int c = blockIdx.x, tid = threadIdx.x;
  double s = (double)p[(size_t)c * 64 + tid];
  for (int d = 32; d > 0; d >>= 1) s += __shfl_down(s, d);
  if (tid == 0) sums[c] = s;
}

// ---------- head: pooled sums -> mean -> fc -> off -> tanh ----------
__global__ __launch_bounds__(128) void head2_kernel(
    const float* __restrict__ pooled, const float* __restrict__ fc_w,
    const float* __restrict__ fc_b, const float* __restrict__ off_w,
    const float* __restrict__ off_b, float* __restrict__ offs) {
  int b = blockIdx.x, tid = threadIdx.x;
  __shared__ float pl[128], feat[128];
  pl[tid] = pooled[(size_t)b * C3 + tid] * (1.0f / 366.0f);
  __syncthreads();
  {
    const float* wr = fc_w + tid * FF;
    float a = fc_b[tid];
    for (int i = 0; i < 128; ++i) a = fmaf(pl[i], wr[i], a);
    feat[tid] = a;
  }
  __syncthreads();
  {
    const float* wr = off_w + tid * FF;
    float z = off_b[tid];
    for (int i = 0; i < 128; ++i) z = fmaf(feat[i], wr[i], z);
    offs[(size_t)b * 128 + tid] = tanhf(z);
  }
}

// ---------- distances + argmin + gather ----------
__global__ __launch_bounds__(256) void dist_kernel(
    const float* __restrict__ x, const float* __restrict__ mask,
    const float* __restrict__ protos, const float* __restrict__ offs,
    float* __restrict__ out) {
  int b = blockIdx.x, tid = threadIdx.x;
  __shared__ float ofl[128];
  __shared__ double dred[256];
  __shared__ int ksel;
  if (tid < 128) ofl[tid] = offs[(size_t)b * 128 + tid];
  __syncthreads();
  int k = tid & 31, tg = tid >> 5;
  float o0 = ofl[k * 4 + 0], o1 = ofl[k * 4 + 1], o2 = ofl[k * 4 + 2], o3 = ofl[k * 4 + 3];
  double acc = 0.0;
  for (int t = tg; t < TIN; t += 8) {
    float4 xv = *(const float4*)(x + ((size_t)b * TIN + t) * 4);
    float4 pv = *(const float4*)(protos + ((size_t)k * TIN + t) * 4);
    float m = mask[(size_t)b * TIN + t];
    float d0 = xv.x - pv.x - o0;
    float d1 = xv.y - pv.y - o1;
    float d2 = xv.z - pv.z - o2;
    float d3 = xv.w - pv.w - o3;
    acc += (double)(m * (d0 * d0 + d1 * d1 + d2 * d2 + d3 * d3));
  }
  dred[tid] = acc;
  __syncthreads();
  if (tid < 32) {
    double s = 0.0;
    for (int g = 0; g < 8; ++g) s += dred[g * 32 + tid];
    dred[tid] = s;
  }
  __syncthreads();
  if (tid == 0) {
    double best = dred[0]; int bi = 0;
    for (int kk = 1; kk < 32; ++kk)
      if (dred[kk] < best) { best = dred[kk]; bi = kk; }  // strict < = first-min
    ksel = bi;
  }
  __syncthreads();
  int km = ksel;
  const float* psrc = protos + (size_t)km * TIN * 4;
  float* dst = out + (size_t)b * TIN * 4;
  for (int u = tid; u < TIN * 4; u += 256)
    dst[u] = psrc[u] + ofl[km * 4 + (u & 3)];
}

extern "C" void kernel_launch(void* const* d_in, const int* in_sizes, int n_in,
                              void* d_out, int out_size, void* d_ws, size_t ws_size,
                              hipStream_t stream) {
  const float* x      = (const float*)d_in[0];
  const float* mask   = (const float*)d_in[2];
  const float* protos = (const float*)d_in[3];
  const float* w1 = (const float*)d_in[4];
  const float* b1 = (const float*)d_in[5];
  const float* g1 = (const float*)d_in[6];
  const float* be1 = (const float*)d_in[7];
  const float* w2 = (const float*)d_in[8];
  const float* b2 = (const float*)d_in[9];
  const float* g2 = (const float*)d_in[10];
  const float* be2 = (const float*)d_in[11];
  const float* w3 = (const float*)d_in[12];
  const float* b3 = (const float*)d_in[13];
  const float* g3 = (const float*)d_in[14];
  const float* be3 = (const float*)d_in[15];
  const float* fc_w = (const float*)d_in[16];
  const float* fc_b = (const float*)d_in[17];
  const float* off_w = (const float*)d_in[18];
  const float* off_b = (const float*)d_in[19];
  float* out = (float*)d_out;
  (void)in_sizes; (void)n_in; (void)out_size;

  char* wsp = (char*)d_ws;
  size_t off = 0;
  auto alloc = [&](size_t bytes) { void* p = wsp + off; off += (bytes + 255) & ~(size_t)255; return p; };
  float* bnp   = (float*)alloc(1024 * 4);
  float* offs  = (float*)alloc((size_t)BB * 128 * 4);
  size_t zero_beg = off;
  double* sums  = (double*)alloc(1024 * 8);
  float* pooled = (float*)alloc((size_t)BB * C3 * 4);
  float* p2     = (float*)alloc((size_t)512 * 64 * 4);
  float* p3     = (float*)alloc((size_t)256 * 64 * 4);
  size_t zero_end = off;
  short* w2ph = (short*)alloc((size_t)256 * 128 * 5 * 2);
  short* w2pl = (short*)alloc((size_t)256 * 128 * 5 * 2);
  short* w3ph = (short*)alloc((size_t)128 * 256 * 3 * 2);
  short* w3pl = (short*)alloc((size_t)128 * 256 * 3 * 2);
  size_t small_end = off;
  const size_t h3_bytes = (size_t)BB * 128 * 368 * 4;   // 386 MB fp32, lossless
  float* h3g = (float*)(wsp + small_end);
  const bool h3_ok = ws_size >= small_end + h3_bytes;

  double* sums1 = sums;
  double* sums2 = sums + 256;
  double* sums3 = sums + 768;
  float* scale1 = bnp;        float* shift1 = bnp + 128;
  float* scale2 = bnp + 256;  float* shift2 = bnp + 512;
  float* scale3 = bnp + 768;  float* shift3 = bnp + 896;

  hipMemsetAsync(wsp + zero_beg, 0, zero_end - zero_beg, stream);

  conv1_stats_kernel<<<256, 256, 0, stream>>>(x, w1, b1, sums1);
  bnparam_kernel<<<1, 256, 0, stream>>>(sums1, g1, be1, C1, scale1, shift1);

  wprep2_kernel<<<256, 256, 0, stream>>>(w2, w2ph, w2pl);
  wprep3_kernel<<<128, 256, 0, stream>>>(w3, w3ph, w3pl);

  conv2_mfma_kernel<<<dim3(6, BB), 256, 0, stream>>>(
      x, w1, b1, scale1, shift1, w2ph, w2pl, b2, p2);
  reduce_slices_kernel<<<512, 64, 0, stream>>>(p2, sums2);
  bnparam_kernel<<<1, 256, 0, stream>>>(sums2, g2, be2, C2, scale2, shift2);

  if (h3_ok) {
    fused23_kernel<0, true><<<dim3(6, BB), 256, 0, stream>>>(
        x, w1, b1, scale1, shift1, w2ph, w2pl, b2, scale2, shift2,
        w3ph, w3pl, b3, scale3, shift3, p3, pooled, h3g);
    reduce_slices_kernel<<<256, 64, 0, stream>>>(p3, sums3);
    bnparam_kernel<<<1, 256, 0, stream>>>(sums3, g3, be3, C3, scale3, shift3);
    gap3_kernel<<<BB, 256, 0, stream>>>(h3g, scale3, shift3, pooled);
  } else {
    fused23_kernel<0, false><<<dim3(6, BB), 256, 0, stream>>>(
        x, w1, b1, scale1, shift1, w2ph, w2pl, b2, scale2, shift2,
        w3ph, w3pl, b3, scale3, shift3, p3, pooled, h3g);
    reduce_slices_kernel<<<256, 64, 0, stream>>>(p3, sums3);
    bnparam_kernel<<<1, 256, 0, stream>>>(sums3, g3, be3, C3, scale3, shift3);
    fused23_kernel<1, false><<<dim3(6, BB), 256, 0, stream>>>(
        x, w1, b1, scale1, shift1, w2ph, w2pl, b2, scale2, shift2,
        w3ph, w3pl, b3, scale3, shift3, p3, pooled, h3g);
  }

  head2_kernel<<<BB, 128, 0, stream>>>(pooled, fc_w, fc_b, off_w, off_b, offs);
  dist_kernel<<<BB, 256, 0, stream>>>(x, mask, protos, offs, out);
}